// Round 2
// baseline (850.511 us; speedup 1.0000x reference)
//
#include <hip/hip_runtime.h>

typedef float f4 __attribute__((ext_vector_type(4)));

namespace {
constexpr int B = 16;
constexpr int C = 16;
}

// ---------------------------------------------------------------------------
// Pass 1: channel-major img[bb][c][y][x] -> channels-last ws[bb][y][x][c].
// 4 lanes per pixel: lane quad q handles channels 4q..4q+3.
//   reads : instr e hits 4 channel planes x 16 consecutive pixels (coalesced)
//   writes: one f4 per lane, contiguous across the wave (1KB/instr, 0 waste)
// ---------------------------------------------------------------------------
template <int S>
__global__ __launch_bounds__(256) void transpose_kernel(
    const float* __restrict__ img, float* __restrict__ ws, int total4)
{
    constexpr int SS = S * S;
    int t = blockIdx.x * 256 + threadIdx.x;
    if (t >= total4) return;
    const int q   = t & 3;
    const int p   = t >> 2;              // chunk-local pixel: bb*SS + rem
    const int bb  = p / SS;
    const int rem = p - bb * SS;

    const float* ip = img + (size_t)bb * C * SS + (size_t)(4 * q) * SS + rem;
    f4 v;
    v.x = __builtin_nontemporal_load(&ip[0]);          // img is read exactly once
    v.y = __builtin_nontemporal_load(&ip[SS]);
    v.z = __builtin_nontemporal_load(&ip[2 * SS]);
    v.w = __builtin_nontemporal_load(&ip[3 * SS]);
    *(f4*)(ws + (size_t)p * C + 4 * q) = v;            // keep cached: re-read by gather
}

// ---------------------------------------------------------------------------
// Pass 2: gather, 4 lanes per pixel. Each tap = ONE dwordx4 per lane; the 4
// lanes of a quad cover the tap's full 64B line -> TA merges to 1 line/tap.
// Zero-weight row pairs are skipped (uniform within the quad).
// ---------------------------------------------------------------------------
template <int S>
__global__ __launch_bounds__(256) void gather_kernel(
    const float* __restrict__ ws, const float* __restrict__ flow,
    float* __restrict__ out, int total4)
{
    constexpr int SS = S * S;
    int t = blockIdx.x * 256 + threadIdx.x;
    if (t >= total4) return;
    const int q   = t & 3;
    const int p   = t >> 2;
    const int bb  = p / SS;
    const int rem = p - bb * SS;
    const int i   = rem / S;
    const int j   = rem - i * S;

    const float f0 = flow[(size_t)bb * 2 * SS + rem];       // channel 0
    const float f1 = flow[(size_t)bb * 2 * SS + SS + rem];  // channel 1

    const float sm1 = (float)(S - 1);
    // identical op order to the verified kernel (incl. the (i-1) offset)
    const float gx = -1.0f + ((float)i - 1.0f) / sm1 * 2.0f + f0;
    const float gy = -1.0f + ((float)j - 1.0f) / sm1 * 2.0f + f1;
    const float x = (gx + 1.0f) * 0.5f * sm1;
    const float y = (gy + 1.0f) * 0.5f * sm1;

    const float x0f = floorf(x), y0f = floorf(y);
    const float x1f = x0f + 1.0f, y1f = y0f + 1.0f;
    const float wx1 = x - x0f, wx0 = 1.0f - wx1;
    const float wy1 = y - y0f, wy0 = 1.0f - wy1;

    const bool bx0 = (x0f >= 0.0f) && (x0f <= sm1);
    const bool bx1 = (x1f >= 0.0f) && (x1f <= sm1);
    const bool by0 = (y0f >= 0.0f) && (y0f <= sm1);
    const bool by1 = (y1f >= 0.0f) && (y1f <= sm1);

    const int xc0 = (int)fminf(fmaxf(x0f, 0.0f), sm1);
    const int xc1 = (int)fminf(fmaxf(x1f, 0.0f), sm1);
    const int yc0 = (int)fminf(fmaxf(y0f, 0.0f), sm1);
    const int yc1 = (int)fminf(fmaxf(y1f, 0.0f), sm1);

    const float w00 = (by0 && bx0) ? wy0 * wx0 : 0.0f;
    const float w01 = (by0 && bx1) ? wy0 * wx1 : 0.0f;
    const float w10 = (by1 && bx0) ? wy1 * wx0 : 0.0f;
    const float w11 = (by1 && bx1) ? wy1 * wx1 : 0.0f;

    const float* base = ws + (size_t)bb * SS * C + 4 * q;
    f4 a = {0.f, 0.f, 0.f, 0.f};

    if (w00 != 0.0f || w01 != 0.0f) {        // top row pair
        f4 t0 = *(const f4*)(base + (size_t)(yc0 * S + xc0) * C);
        f4 t1 = *(const f4*)(base + (size_t)(yc0 * S + xc1) * C);
        a += w00 * t0 + w01 * t1;
    }
    if (w10 != 0.0f || w11 != 0.0f) {        // bottom row pair
        f4 t0 = *(const f4*)(base + (size_t)(yc1 * S + xc0) * C);
        f4 t1 = *(const f4*)(base + (size_t)(yc1 * S + xc1) * C);
        a += w10 * t0 + w11 * t1;
    }

    float* ob = out + (size_t)bb * C * SS + (size_t)(4 * q) * SS + rem;
    __builtin_nontemporal_store(a.x, &ob[0]);       // out never re-read
    __builtin_nontemporal_store(a.y, &ob[SS]);
    __builtin_nontemporal_store(a.z, &ob[2 * SS]);
    __builtin_nontemporal_store(a.w, &ob[3 * SS]);
}

// ---------------------------------------------------------------------------
// Fallback (ws too small): fused kernel + zero-weight full skip.
// ---------------------------------------------------------------------------
template <int S>
__global__ __launch_bounds__(256) void warp_fallback(
    const float* __restrict__ img, const float* __restrict__ flow,
    float* __restrict__ out, int total)
{
    constexpr int SS = S * S;
    int idx = blockIdx.x * 256 + threadIdx.x;
    if (idx >= total) return;
    const int b   = idx / SS;
    const int rem = idx - b * SS;
    const int i   = rem / S;
    const int j   = rem - i * S;

    const float f0 = flow[(size_t)b * 2 * SS + rem];
    const float f1 = flow[(size_t)b * 2 * SS + SS + rem];

    const float sm1 = (float)(S - 1);
    const float gx = -1.0f + ((float)i - 1.0f) / sm1 * 2.0f + f0;
    const float gy = -1.0f + ((float)j - 1.0f) / sm1 * 2.0f + f1;
    const float x = (gx + 1.0f) * 0.5f * sm1;
    const float y = (gy + 1.0f) * 0.5f * sm1;

    const float x0f = floorf(x), y0f = floorf(y);
    const float x1f = x0f + 1.0f, y1f = y0f + 1.0f;
    const float wx1 = x - x0f, wx0 = 1.0f - wx1;
    const float wy1 = y - y0f, wy0 = 1.0f - wy1;

    const bool bx0 = (x0f >= 0.0f) && (x0f <= sm1);
    const bool bx1 = (x1f >= 0.0f) && (x1f <= sm1);
    const bool by0 = (y0f >= 0.0f) && (y0f <= sm1);
    const bool by1 = (y1f >= 0.0f) && (y1f <= sm1);

    const int xc0 = (int)fminf(fmaxf(x0f, 0.0f), sm1);
    const int xc1 = (int)fminf(fmaxf(x1f, 0.0f), sm1);
    const int yc0 = (int)fminf(fmaxf(y0f, 0.0f), sm1);
    const int yc1 = (int)fminf(fmaxf(y1f, 0.0f), sm1);

    const float w00 = (by0 && bx0) ? wy0 * wx0 : 0.0f;
    const float w01 = (by0 && bx1) ? wy0 * wx1 : 0.0f;
    const float w10 = (by1 && bx0) ? wy1 * wx0 : 0.0f;
    const float w11 = (by1 && bx1) ? wy1 * wx1 : 0.0f;

    const int o00 = yc0 * S + xc0;
    const int o01 = yc0 * S + xc1;
    const int o10 = yc1 * S + xc0;
    const int o11 = yc1 * S + xc1;

    const float* ib = img + (size_t)b * C * SS;
    float*       ob = out + (size_t)b * C * SS + rem;

    if (w00 + w01 + w10 + w11 != 0.0f) {
#pragma unroll 4
        for (int c = 0; c < C; ++c) {
            const float* pp = ib + (size_t)c * SS;
            ob[(size_t)c * SS] =
                w00 * pp[o00] + w01 * pp[o01] + w10 * pp[o10] + w11 * pp[o11];
        }
    } else {
#pragma unroll 4
        for (int c = 0; c < C; ++c) ob[(size_t)c * SS] = 0.0f;
    }
}

// ---------------------------------------------------------------------------
template <int S>
static void run_scale(const float* img, const float* flow, float* out,
                      float* ws, size_t ws_size, hipStream_t stream)
{
    constexpr int SS = S * S;
    const size_t per_b = (size_t)SS * C * sizeof(float);

    // keep ws L3-resident between transpose and gather: cap footprint ~32MB
    int chunk = (int)((32u << 20) / per_b);
    if (chunk < 1) chunk = 1;
    if (chunk > B) chunk = B;
    if (ws == nullptr || ws_size < per_b) chunk = 0;
    while (chunk >= 1 && (size_t)chunk * per_b > ws_size) chunk >>= 1;

    if (chunk >= 1) {
        for (int b0 = 0; b0 < B; b0 += chunk) {
            const int nb     = (b0 + chunk <= B) ? chunk : (B - b0);
            const int total4 = nb * SS * 4;          // 4 lanes per pixel
            const int grid   = (total4 + 255) / 256;
            transpose_kernel<S><<<grid, 256, 0, stream>>>(
                img + (size_t)b0 * C * SS, ws, total4);
            gather_kernel<S><<<grid, 256, 0, stream>>>(
                ws, flow + (size_t)b0 * 2 * SS,
                out + (size_t)b0 * C * SS, total4);
        }
    } else {
        const int total = B * SS;
        warp_fallback<S><<<(total + 255) / 256, 256, 0, stream>>>(
            img, flow, out, total);
    }
}

extern "C" void kernel_launch(void* const* d_in, const int* /*in_sizes*/, int /*n_in*/,
                              void* d_out, int /*out_size*/, void* d_ws, size_t ws_size,
                              hipStream_t stream)
{
    float* out = (float*)d_out;
    float* ws  = (float*)d_ws;

    run_scale<512>((const float*)d_in[0], (const float*)d_in[1], out, ws, ws_size, stream);
    out += (size_t)B * C * 512 * 512;
    run_scale<256>((const float*)d_in[2], (const float*)d_in[3], out, ws, ws_size, stream);
    out += (size_t)B * C * 256 * 256;
    run_scale<128>((const float*)d_in[4], (const float*)d_in[5], out, ws, ws_size, stream);
    out += (size_t)B * C * 128 * 128;
    run_scale<64>((const float*)d_in[6], (const float*)d_in[7], out, ws, ws_size, stream);
}

// Round 3
// 831.766 us; speedup vs baseline: 1.0225x; 1.0225x over previous
//
#include <hip/hip_runtime.h>

typedef float f4 __attribute__((ext_vector_type(4)));

namespace {
constexpr int B = 16;
constexpr int C = 16;
}

// ---------------------------------------------------------------------------
// Pass 1: channel-major img[bb][c][y][x] -> channels-last ws[bb][y][x][c].
// 4 lanes per pixel: lane quad q handles channels 4q..4q+3.
// ---------------------------------------------------------------------------
template <int S>
__global__ __launch_bounds__(256) void transpose_kernel(
    const float* __restrict__ img, float* __restrict__ ws, int total4)
{
    constexpr int SS = S * S;
    int t = blockIdx.x * 256 + threadIdx.x;
    if (t >= total4) return;
    const int q   = t & 3;
    const int p   = t >> 2;              // pixel: bb*SS + rem
    const int bb  = p / SS;
    const int rem = p - bb * SS;

    const float* ip = img + (size_t)bb * C * SS + (size_t)(4 * q) * SS + rem;
    f4 v;
    v.x = __builtin_nontemporal_load(&ip[0]);          // img read exactly once
    v.y = __builtin_nontemporal_load(&ip[SS]);
    v.z = __builtin_nontemporal_load(&ip[2 * SS]);
    v.w = __builtin_nontemporal_load(&ip[3 * SS]);
    *(f4*)(ws + (size_t)p * C + 4 * q) = v;            // cached: re-read by gather
}

// ---------------------------------------------------------------------------
// Pass 2: gather, 4 lanes per pixel. Each tap = ONE dwordx4 per lane; a quad
// covers the tap's full 64B line. Zero-weight row pairs skipped (quad-uniform).
// ---------------------------------------------------------------------------
template <int S>
__global__ __launch_bounds__(256) void gather_kernel(
    const float* __restrict__ ws, const float* __restrict__ flow,
    float* __restrict__ out, int total4)
{
    constexpr int SS = S * S;
    int t = blockIdx.x * 256 + threadIdx.x;
    if (t >= total4) return;
    const int q   = t & 3;
    const int p   = t >> 2;
    const int bb  = p / SS;
    const int rem = p - bb * SS;
    const int i   = rem / S;
    const int j   = rem - i * S;

    const float f0 = flow[(size_t)bb * 2 * SS + rem];       // channel 0
    const float f1 = flow[(size_t)bb * 2 * SS + SS + rem];  // channel 1

    const float sm1 = (float)(S - 1);
    // identical op order to the verified kernel (incl. the (i-1) offset)
    const float gx = -1.0f + ((float)i - 1.0f) / sm1 * 2.0f + f0;
    const float gy = -1.0f + ((float)j - 1.0f) / sm1 * 2.0f + f1;
    const float x = (gx + 1.0f) * 0.5f * sm1;
    const float y = (gy + 1.0f) * 0.5f * sm1;

    const float x0f = floorf(x), y0f = floorf(y);
    const float x1f = x0f + 1.0f, y1f = y0f + 1.0f;
    const float wx1 = x - x0f, wx0 = 1.0f - wx1;
    const float wy1 = y - y0f, wy0 = 1.0f - wy1;

    const bool bx0 = (x0f >= 0.0f) && (x0f <= sm1);
    const bool bx1 = (x1f >= 0.0f) && (x1f <= sm1);
    const bool by0 = (y0f >= 0.0f) && (y0f <= sm1);
    const bool by1 = (y1f >= 0.0f) && (y1f <= sm1);

    const int xc0 = (int)fminf(fmaxf(x0f, 0.0f), sm1);
    const int xc1 = (int)fminf(fmaxf(x1f, 0.0f), sm1);
    const int yc0 = (int)fminf(fmaxf(y0f, 0.0f), sm1);
    const int yc1 = (int)fminf(fmaxf(y1f, 0.0f), sm1);

    const float w00 = (by0 && bx0) ? wy0 * wx0 : 0.0f;
    const float w01 = (by0 && bx1) ? wy0 * wx1 : 0.0f;
    const float w10 = (by1 && bx0) ? wy1 * wx0 : 0.0f;
    const float w11 = (by1 && bx1) ? wy1 * wx1 : 0.0f;

    const float* base = ws + (size_t)bb * SS * C + 4 * q;
    f4 a = {0.f, 0.f, 0.f, 0.f};

    if (w00 != 0.0f || w01 != 0.0f) {        // top row pair
        f4 t0 = *(const f4*)(base + (size_t)(yc0 * S + xc0) * C);
        f4 t1 = *(const f4*)(base + (size_t)(yc0 * S + xc1) * C);
        a += w00 * t0 + w01 * t1;
    }
    if (w10 != 0.0f || w11 != 0.0f) {        // bottom row pair
        f4 t0 = *(const f4*)(base + (size_t)(yc1 * S + xc0) * C);
        f4 t1 = *(const f4*)(base + (size_t)(yc1 * S + xc1) * C);
        a += w10 * t0 + w11 * t1;
    }

    float* ob = out + (size_t)bb * C * SS + (size_t)(4 * q) * SS + rem;
    __builtin_nontemporal_store(a.x, &ob[0]);       // out never re-read
    __builtin_nontemporal_store(a.y, &ob[SS]);
    __builtin_nontemporal_store(a.z, &ob[2 * SS]);
    __builtin_nontemporal_store(a.w, &ob[3 * SS]);
}

// ---------------------------------------------------------------------------
// Fused one-pass kernel (tap-skip). Used for S<=128 where img fits aggregate
// L2, making the transpose's extra traffic + launches a net loss. Also the
// fallback when ws is unusable.
// ---------------------------------------------------------------------------
template <int S>
__global__ __launch_bounds__(256) void warp_fused(
    const float* __restrict__ img, const float* __restrict__ flow,
    float* __restrict__ out, int total)
{
    constexpr int SS = S * S;
    int idx = blockIdx.x * 256 + threadIdx.x;
    if (idx >= total) return;
    const int b   = idx / SS;
    const int rem = idx - b * SS;
    const int i   = rem / S;
    const int j   = rem - i * S;

    const float f0 = flow[(size_t)b * 2 * SS + rem];
    const float f1 = flow[(size_t)b * 2 * SS + SS + rem];

    const float sm1 = (float)(S - 1);
    const float gx = -1.0f + ((float)i - 1.0f) / sm1 * 2.0f + f0;
    const float gy = -1.0f + ((float)j - 1.0f) / sm1 * 2.0f + f1;
    const float x = (gx + 1.0f) * 0.5f * sm1;
    const float y = (gy + 1.0f) * 0.5f * sm1;

    const float x0f = floorf(x), y0f = floorf(y);
    const float x1f = x0f + 1.0f, y1f = y0f + 1.0f;
    const float wx1 = x - x0f, wx0 = 1.0f - wx1;
    const float wy1 = y - y0f, wy0 = 1.0f - wy1;

    const bool bx0 = (x0f >= 0.0f) && (x0f <= sm1);
    const bool bx1 = (x1f >= 0.0f) && (x1f <= sm1);
    const bool by0 = (y0f >= 0.0f) && (y0f <= sm1);
    const bool by1 = (y1f >= 0.0f) && (y1f <= sm1);

    const int xc0 = (int)fminf(fmaxf(x0f, 0.0f), sm1);
    const int xc1 = (int)fminf(fmaxf(x1f, 0.0f), sm1);
    const int yc0 = (int)fminf(fmaxf(y0f, 0.0f), sm1);
    const int yc1 = (int)fminf(fmaxf(y1f, 0.0f), sm1);

    const float w00 = (by0 && bx0) ? wy0 * wx0 : 0.0f;
    const float w01 = (by0 && bx1) ? wy0 * wx1 : 0.0f;
    const float w10 = (by1 && bx0) ? wy1 * wx0 : 0.0f;
    const float w11 = (by1 && bx1) ? wy1 * wx1 : 0.0f;

    const int o00 = yc0 * S + xc0;
    const int o01 = yc0 * S + xc1;
    const int o10 = yc1 * S + xc0;
    const int o11 = yc1 * S + xc1;

    const float* ib = img + (size_t)b * C * SS;
    float*       ob = out + (size_t)b * C * SS + rem;

    if (w00 + w01 + w10 + w11 != 0.0f) {
#pragma unroll 4
        for (int c = 0; c < C; ++c) {
            const float* pp = ib + (size_t)c * SS;
            ob[(size_t)c * SS] =
                w00 * pp[o00] + w01 * pp[o01] + w10 * pp[o10] + w11 * pp[o11];
        }
    } else {
#pragma unroll 4
        for (int c = 0; c < C; ++c) ob[(size_t)c * SS] = 0.0f;
    }
}

// ---------------------------------------------------------------------------
template <int S>
static void run_two_pass(const float* img, const float* flow, float* out,
                         float* ws, size_t ws_size, hipStream_t stream)
{
    constexpr int SS = S * S;
    const size_t per_b = (size_t)SS * C * sizeof(float);

    int chunk = B;                                    // single-shot preferred
    if (ws == nullptr || ws_size < per_b) chunk = 0;
    while (chunk >= 1 && (size_t)chunk * per_b > ws_size) chunk >>= 1;

    if (chunk >= 1) {
        for (int b0 = 0; b0 < B; b0 += chunk) {
            const int nb     = (b0 + chunk <= B) ? chunk : (B - b0);
            const int total4 = nb * SS * 4;
            const int grid   = (total4 + 255) / 256;
            transpose_kernel<S><<<grid, 256, 0, stream>>>(
                img + (size_t)b0 * C * SS, ws, total4);
            gather_kernel<S><<<grid, 256, 0, stream>>>(
                ws, flow + (size_t)b0 * 2 * SS,
                out + (size_t)b0 * C * SS, total4);
        }
    } else {
        const int total = B * SS;
        warp_fused<S><<<(total + 255) / 256, 256, 0, stream>>>(
            img, flow, out, total);
    }
}

template <int S>
static void run_fused(const float* img, const float* flow, float* out,
                      hipStream_t stream)
{
    const int total = B * S * S;
    warp_fused<S><<<(total + 255) / 256, 256, 0, stream>>>(img, flow, out, total);
}

extern "C" void kernel_launch(void* const* d_in, const int* /*in_sizes*/, int /*n_in*/,
                              void* d_out, int /*out_size*/, void* d_ws, size_t ws_size,
                              hipStream_t stream)
{
    float* out = (float*)d_out;
    float* ws  = (float*)d_ws;

    // S=512/256: two-pass (img >> L2, channels-last restaging pays off)
    run_two_pass<512>((const float*)d_in[0], (const float*)d_in[1], out, ws, ws_size, stream);
    out += (size_t)B * C * 512 * 512;
    run_two_pass<256>((const float*)d_in[2], (const float*)d_in[3], out, ws, ws_size, stream);
    out += (size_t)B * C * 256 * 256;
    // S=128/64: img fits aggregate L2 -> fused single pass
    run_fused<128>((const float*)d_in[4], (const float*)d_in[5], out, stream);
    out += (size_t)B * C * 128 * 128;
    run_fused<64>((const float*)d_in[6], (const float*)d_in[7], out, stream);
}